// Round 7
// baseline (361.372 us; speedup 1.0000x reference)
//
#include <hip/hip_runtime.h>

typedef __attribute__((ext_vector_type(8))) short short8;
typedef __attribute__((ext_vector_type(4))) short s4v;
typedef __attribute__((ext_vector_type(4))) float floatx4;

#define SPOS 16384

// round-to-nearest-even fp32 -> bf16 bits
__device__ __forceinline__ unsigned short f2bf(float f) {
    unsigned u = __float_as_uint(f);
    u += 0x7fffu + ((u >> 16) & 1u);
    return (unsigned short)(u >> 16);
}

// Branchless bit-twiddle posit quantizer (verified equivalent of the 128
// sequential where-passes).
__device__ __forceinline__ float posit_q(float x) {
    unsigned xu  = __float_as_uint(x);
    unsigned sgn = xu & 0x80000000u;
    unsigned au  = xu & 0x7fffffffu;
    unsigned m   = au & 0x007fffffu;
    unsigned r   = (au + 0x00080000u) & 0xfff00000u;
    bool bdry = (m & 0x000fffffu) == 0x00080000u;
    unsigned res;
    if (au >= 0x3f800000u) {                      // |x| >= 1
        res = r;
        if (m > 0x00700000u && m < 0x00780000u && au < 0x47700000u)
            res = (au & 0xff800000u) + 0x00800000u;   // -> 2^(E+1)
        if ((bdry && m != 0x00780000u) || au >= 0x47780000u)
            res = au;                              // boundaries & clamp unchanged
    } else {                                       // |x| < 1
        res = (m <= 0x00080000u || m >= 0x00780000u || bdry) ? au : r;
        if (au < 0x37880000u) res = au ? 0x37800000u : 0u;  // -> 2^-16 (0 stays 0)
    }
    return __uint_as_float(sgn | res);
}

// Same, for z >= 0 (post-ReLU) — sign handling dropped, bit-identical result.
__device__ __forceinline__ float posit_q_pos(float z) {
    unsigned au  = __float_as_uint(z);
    unsigned m   = au & 0x007fffffu;
    unsigned r   = (au + 0x00080000u) & 0xfff00000u;
    bool bdry = (m & 0x000fffffu) == 0x00080000u;
    unsigned res;
    if (au >= 0x3f800000u) {
        res = r;
        if (m > 0x00700000u && m < 0x00780000u && au < 0x47700000u)
            res = (au & 0xff800000u) + 0x00800000u;
        if ((bdry && m != 0x00780000u) || au >= 0x47780000u)
            res = au;
    } else {
        res = (m <= 0x00080000u || m >= 0x00780000u || bdry) ? au : r;
        if (au < 0x37880000u) res = au ? 0x37800000u : 0u;
    }
    return __uint_as_float(res);
}

// Quantize weights to bf16 in MFMA-FRAGMENT-PACKED order + fold BN constants.
// Packed layout: i = G*4096 + kb*512 + lane*8 + j  (G=row-group of 16, kb=K-block
// of 32, lane=wave lane, j=0..7) holds W[16G + (lane&15)][32kb + 8*(lane>>4) + j].
__global__ __launch_bounds__(256) void prep_kernel(
    const float* __restrict__ w1, const float* __restrict__ w2,
    const float* __restrict__ b1, const float* __restrict__ g1,
    const float* __restrict__ be1, const float* __restrict__ m1,
    const float* __restrict__ v1,
    const float* __restrict__ b2, const float* __restrict__ g2,
    const float* __restrict__ be2, const float* __restrict__ m2,
    const float* __restrict__ v2,
    unsigned short* __restrict__ w1p, unsigned short* __restrict__ w2p,
    float* __restrict__ cst)
{
    int i = blockIdx.x * 256 + threadIdx.x;
    if (i < 65536) {
        const int j    = i & 7;
        const int lane = (i >> 3) & 63;
        const int kb   = (i >> 9) & 7;
        const int G    = i >> 12;
        const int row  = 16 * G + (lane & 15);
        const int k    = 32 * kb + 8 * (lane >> 4) + j;
        w1p[i] = f2bf(posit_q(w1[row * 256 + k]));
        w2p[i] = f2bf(posit_q(w2[row * 256 + k]));
        if (i < 256) {
            float inv1 = g1[i] / sqrtf(v1[i] + 1e-5f);
            cst[i]       = inv1;
            cst[256 + i] = fmaf(b1[i], inv1, be1[i] - m1[i] * inv1);
            float inv2 = g2[i] / sqrtf(v2[i] + 1e-5f);
            cst[512 + i] = inv2;
            cst[768 + i] = fmaf(b2[i], inv2, be2[i] - m2[i] * inv2);
        }
    }
}

// q layout: 64 rows (p) x 32 column-blocks of 8 bf16, XOR-swizzled:
// block cb stored at physical block (cb ^ (p & 31)) -> all LDS ops bank-minimal.
__device__ __forceinline__ int qidx(int p, int cb) {
    return p * 256 + ((cb ^ (p & 31)) << 3);
}

// One block: 64 positions x all 256 channels; both GEMMs fused through LDS.
// LDS = 32 KB (q only; xs transpose buffer ELIMINATED by transposed scalar
// loads in phase 1). launch_bounds(256,3): ~170 unified regs/wave, no spills
// (R2: (256,4) -> 128-reg cap -> scratch spills, +42MB WRITE; not worth it).
__global__ __launch_bounds__(256, 3) void fused_kernel(
    const float* __restrict__ x,
    const unsigned short* __restrict__ w1p,
    const unsigned short* __restrict__ w2p,
    const float* __restrict__ cst,
    float* __restrict__ out)
{
    __shared__ alignas(16) unsigned short q[64 * 256];  // 32 KB, swizzled

    const int b  = blockIdx.x;          // 2048 blocks
    const int n  = b >> 8;
    const int s0 = (b & 255) << 6;
    const float* xb = x   + (size_t)n * (256 * SPOS) + s0;
    float*       ob = out + (size_t)n * (256 * SPOS) + s0;

    const int t    = threadIdx.x;
    const int lane = t & 63;
    const int w    = t >> 6;            // wave id 0..3
    const int quad = lane >> 4;
    const int l15  = lane & 15;

    // ---- Phase 1 (no barriers, no LDS transpose): wave w owns channels
    // 64w..64w+63. Thread (w,lane) builds q row p=lane, blocks cb=8w+r:
    // loads the 8 channels it packs DIRECTLY -- x[64w+8r+c8][s0+lane].
    // Each load instruction: 64 lanes x consecutive positions = 256 B
    // coalesced. Rolling depth-8 register window (16 floats live) pipelines
    // HBM latency; quantize+pack straight from registers -> one ds_write.
    {
        const float* src = xb + (size_t)(64 * w) * SPOS + lane;
        float ld[8];
        #pragma unroll
        for (int c8 = 0; c8 < 8; ++c8)
            ld[c8] = src[(size_t)c8 * SPOS];
        #pragma unroll
        for (int r = 0; r < 8; ++r) {
            float cur[8];
            #pragma unroll
            for (int c8 = 0; c8 < 8; ++c8) cur[c8] = ld[c8];
            if (r < 7) {
                #pragma unroll
                for (int c8 = 0; c8 < 8; ++c8)
                    ld[c8] = src[(size_t)(8 * (r + 1) + c8) * SPOS];
            }
            short8 pk;
            #pragma unroll
            for (int c8 = 0; c8 < 8; ++c8)
                pk[c8] = (short)f2bf(posit_q(cur[c8]));
            *(short8*)&q[qidx(lane, 8 * w + r)] = pk;   // cb = (64w+8r)/8
        }
    }
    __syncthreads();    // q fully populated

    floatx4 acc[4][4];
    #pragma unroll
    for (int i = 0; i < 4; ++i)
        #pragma unroll
        for (int jj = 0; jj < 4; ++jj)
            acc[i][jj] = (floatx4)0.0f;

    // ---- GEMM1: A = W1p (packed, coalesced, L2-hot), B = q ----
    // Depth-2 af rotation: step kk+1's weight loads issue BEFORE step kk's
    // MFMAs (measured neutral on MfmaUtil but harmless; regs allow).
    {
        short8 af[2][4], bf[4];
        #pragma unroll
        for (int i = 0; i < 4; ++i)
            af[0][i] = *(const short8*)&w1p[(((w * 4 + i) * 8 + 0) * 64 + lane) * 8];
        #pragma unroll
        for (int kk = 0; kk < 8; ++kk) {
            const int cur = kk & 1, nxt = cur ^ 1;
            if (kk < 7) {
                #pragma unroll
                for (int i = 0; i < 4; ++i)
                    af[nxt][i] = *(const short8*)&w1p[(((w * 4 + i) * 8 + (kk + 1)) * 64 + lane) * 8];
            }
            #pragma unroll
            for (int jj = 0; jj < 4; ++jj)
                bf[jj] = *(const short8*)&q[qidx(16 * jj + l15, 4 * kk + quad)];
            #pragma unroll
            for (int i = 0; i < 4; ++i)
                #pragma unroll
                for (int jj = 0; jj < 4; ++jj)
                    acc[i][jj] = __builtin_amdgcn_mfma_f32_16x16x32_bf16(af[cur][i], bf[jj], acc[i][jj], 0, 0, 0);
        }
    }

    // Prefetch GEMM2's first af set; completes at the barrier drain, lives
    // in regs through epilogue 1.
    short8 af20[4];
    #pragma unroll
    for (int i = 0; i < 4; ++i)
        af20[i] = *(const short8*)&w2p[(((w * 4 + i) * 8 + 0) * 64 + lane) * 8];

    __syncthreads();   // all waves done reading q before overwrite

    const int mbase = w * 64;

    // ---- Epilogue 1: BN1 + ReLU + posit_q -> bf16 back into q[p][m] ----
    {
        const float* sc1 = cst;
        const float* bi1 = cst + 256;
        #pragma unroll
        for (int i = 0; i < 4; ++i) {
            const int m0 = mbase + 16 * i + quad * 4;
            float sc[4], bi[4];
            #pragma unroll
            for (int r = 0; r < 4; ++r) { sc[r] = sc1[m0 + r]; bi[r] = bi1[m0 + r]; }
            #pragma unroll
            for (int jj = 0; jj < 4; ++jj) {
                const int p = 16 * jj + l15;
                s4v h;
                #pragma unroll
                for (int r = 0; r < 4; ++r) {
                    float z = fmaf(acc[i][jj][r], sc[r], bi[r]);
                    z = fmaxf(z, 0.0f);
                    h[r] = (short)f2bf(posit_q_pos(z));
                }
                *(s4v*)&q[qidx(p, m0 >> 3) + (m0 & 7)] = h;
            }
        }
    }
    __syncthreads();

    // ---- GEMM2 (operand-SWAPPED): acc = mfma(q-frag, W2p-frag) so D is
    // transposed: lane holds 4 consecutive POSITIONS of one channel
    // (verified correct in R6: passed, absmax matches).
    #pragma unroll
    for (int i = 0; i < 4; ++i)
        #pragma unroll
        for (int jj = 0; jj < 4; ++jj)
            acc[i][jj] = (floatx4)0.0f;

    {
        short8 af[2][4], bf[4];
        #pragma unroll
        for (int i = 0; i < 4; ++i)
            af[0][i] = af20[i];
        #pragma unroll
        for (int kk = 0; kk < 8; ++kk) {
            const int cur = kk & 1, nxt = cur ^ 1;
            if (kk < 7) {
                #pragma unroll
                for (int i = 0; i < 4; ++i)
                    af[nxt][i] = *(const short8*)&w2p[(((w * 4 + i) * 8 + (kk + 1)) * 64 + lane) * 8];
            }
            #pragma unroll
            for (int jj = 0; jj < 4; ++jj)
                bf[jj] = *(const short8*)&q[qidx(16 * jj + l15, 4 * kk + quad)];
            #pragma unroll
            for (int i = 0; i < 4; ++i)
                #pragma unroll
                for (int jj = 0; jj < 4; ++jj)
                    acc[i][jj] = __builtin_amdgcn_mfma_f32_16x16x32_bf16(bf[jj], af[cur][i], acc[i][jj], 0, 0, 0);
        }
    }

    // ---- Epilogue 2: BN2 + residual + ReLU -> out, float4-vectorized,
    // PLAIN cached stores (R6: nontemporal caused partial-line writeback,
    // WRITE_SIZE 183->246 MB; normal L2 write-combining merges the four
    // 64B bursts per row into full lines).
    // acc[i][jj][r] = out[ch = 64w+16i+l15][pos = s0 + 16jj + 4*quad + r]
    {
        const float* sc2 = cst + 512;
        const float* bi2 = cst + 768;
        floatx4 res[4][4];
        #pragma unroll
        for (int i = 0; i < 4; ++i) {
            const int ch = mbase + 16 * i + l15;
            const float* xr = xb + (size_t)ch * SPOS + 4 * quad;
            #pragma unroll
            for (int jj = 0; jj < 4; ++jj)
                res[i][jj] = *(const floatx4*)(xr + 16 * jj);
        }
        #pragma unroll
        for (int i = 0; i < 4; ++i) {
            const int ch = mbase + 16 * i + l15;
            const float sc = sc2[ch];
            const float bi = bi2[ch];
            float* orow = ob + (size_t)ch * SPOS + 4 * quad;
            #pragma unroll
            for (int jj = 0; jj < 4; ++jj) {
                floatx4 o;
                #pragma unroll
                for (int r = 0; r < 4; ++r) {
                    float vv = fmaf(acc[i][jj][r], sc, bi) + res[i][jj][r];
                    o[r] = fmaxf(vv, 0.0f);
                }
                *(floatx4*)(orow + 16 * jj) = o;
            }
        }
    }
}

extern "C" void kernel_launch(void* const* d_in, const int* in_sizes, int n_in,
                              void* d_out, int out_size, void* d_ws, size_t ws_size,
                              hipStream_t stream) {
    const float* x   = (const float*)d_in[0];
    const float* w1  = (const float*)d_in[1];
    const float* b1  = (const float*)d_in[2];
    const float* g1  = (const float*)d_in[3];
    const float* be1 = (const float*)d_in[4];
    const float* m1  = (const float*)d_in[5];
    const float* v1  = (const float*)d_in[6];
    const float* w2  = (const float*)d_in[7];
    const float* b2  = (const float*)d_in[8];
    const float* g2  = (const float*)d_in[9];
    const float* be2 = (const float*)d_in[10];
    const float* m2  = (const float*)d_in[11];
    const float* v2  = (const float*)d_in[12];

    unsigned short* w1p = (unsigned short*)d_ws;
    unsigned short* w2p = w1p + 65536;
    float* cst = (float*)(w2p + 65536);   // scale1|bias1|scale2|bias2

    prep_kernel<<<256, 256, 0, stream>>>(w1, w2, b1, g1, be1, m1, v1,
                                         b2, g2, be2, m2, v2, w1p, w2p, cst);
    fused_kernel<<<2048, 256, 0, stream>>>(x, w1p, w2p, cst, (float*)d_out);
}

// Round 8
// 327.544 us; speedup vs baseline: 1.1033x; 1.1033x over previous
//
#include <hip/hip_runtime.h>

typedef __attribute__((ext_vector_type(8))) short short8;
typedef __attribute__((ext_vector_type(4))) short s4v;
typedef __attribute__((ext_vector_type(4))) float floatx4;

#define SPOS 16384

// round-to-nearest-even fp32 -> bf16 bits
__device__ __forceinline__ unsigned short f2bf(float f) {
    unsigned u = __float_as_uint(f);
    u += 0x7fffu + ((u >> 16) & 1u);
    return (unsigned short)(u >> 16);
}

// Branchless bit-twiddle posit quantizer (verified equivalent of the 128
// sequential where-passes).
__device__ __forceinline__ float posit_q(float x) {
    unsigned xu  = __float_as_uint(x);
    unsigned sgn = xu & 0x80000000u;
    unsigned au  = xu & 0x7fffffffu;
    unsigned m   = au & 0x007fffffu;
    unsigned r   = (au + 0x00080000u) & 0xfff00000u;
    bool bdry = (m & 0x000fffffu) == 0x00080000u;
    unsigned res;
    if (au >= 0x3f800000u) {                      // |x| >= 1
        res = r;
        if (m > 0x00700000u && m < 0x00780000u && au < 0x47700000u)
            res = (au & 0xff800000u) + 0x00800000u;   // -> 2^(E+1)
        if ((bdry && m != 0x00780000u) || au >= 0x47780000u)
            res = au;                              // boundaries & clamp unchanged
    } else {                                       // |x| < 1
        res = (m <= 0x00080000u || m >= 0x00780000u || bdry) ? au : r;
        if (au < 0x37880000u) res = au ? 0x37800000u : 0u;  // -> 2^-16 (0 stays 0)
    }
    return __uint_as_float(sgn | res);
}

// Same, for z >= 0 (post-ReLU) — sign handling dropped, bit-identical result.
__device__ __forceinline__ float posit_q_pos(float z) {
    unsigned au  = __float_as_uint(z);
    unsigned m   = au & 0x007fffffu;
    unsigned r   = (au + 0x00080000u) & 0xfff00000u;
    bool bdry = (m & 0x000fffffu) == 0x00080000u;
    unsigned res;
    if (au >= 0x3f800000u) {
        res = r;
        if (m > 0x00700000u && m < 0x00780000u && au < 0x47700000u)
            res = (au & 0xff800000u) + 0x00800000u;
        if ((bdry && m != 0x00780000u) || au >= 0x47780000u)
            res = au;
    } else {
        res = (m <= 0x00080000u || m >= 0x00780000u || bdry) ? au : r;
        if (au < 0x37880000u) res = au ? 0x37800000u : 0u;
    }
    return __uint_as_float(res);
}

// Quantize weights to bf16 in MFMA-FRAGMENT-PACKED order + fold BN constants.
// Packed layout: i = G*4096 + kb*512 + lane*8 + j  (G=row-group of 16, kb=K-block
// of 32, lane=wave lane, j=0..7) holds W[16G + (lane&15)][32kb + 8*(lane>>4) + j].
__global__ __launch_bounds__(256) void prep_kernel(
    const float* __restrict__ w1, const float* __restrict__ w2,
    const float* __restrict__ b1, const float* __restrict__ g1,
    const float* __restrict__ be1, const float* __restrict__ m1,
    const float* __restrict__ v1,
    const float* __restrict__ b2, const float* __restrict__ g2,
    const float* __restrict__ be2, const float* __restrict__ m2,
    const float* __restrict__ v2,
    unsigned short* __restrict__ w1p, unsigned short* __restrict__ w2p,
    float* __restrict__ cst)
{
    int i = blockIdx.x * 256 + threadIdx.x;
    if (i < 65536) {
        const int j    = i & 7;
        const int lane = (i >> 3) & 63;
        const int kb   = (i >> 9) & 7;
        const int G    = i >> 12;
        const int row  = 16 * G + (lane & 15);
        const int k    = 32 * kb + 8 * (lane >> 4) + j;
        w1p[i] = f2bf(posit_q(w1[row * 256 + k]));
        w2p[i] = f2bf(posit_q(w2[row * 256 + k]));
        if (i < 256) {
            float inv1 = g1[i] / sqrtf(v1[i] + 1e-5f);
            cst[i]       = inv1;
            cst[256 + i] = fmaf(b1[i], inv1, be1[i] - m1[i] * inv1);
            float inv2 = g2[i] / sqrtf(v2[i] + 1e-5f);
            cst[512 + i] = inv2;
            cst[768 + i] = fmaf(b2[i], inv2, be2[i] - m2[i] * inv2);
        }
    }
}

// q layout: 64 rows (p) x 32 column-blocks of 8 bf16, XOR-swizzled:
// block cb stored at physical block (cb ^ (p & 31)) -> all LDS ops bank-minimal.
__device__ __forceinline__ int qidx(int p, int cb) {
    return p * 256 + ((cb ^ (p & 31)) << 3);
}

// One block: 64 positions x all 256 channels; both GEMMs fused through LDS.
// LDS = 32 KB (q, reused as f32 staging in epilogue 2) + 16 KB (xs) = 48 KB
// -> 3 blocks/CU. launch_bounds(256,3): ~170 unified regs/wave, no spills.
__global__ __launch_bounds__(256, 3) void fused_kernel(
    const float* __restrict__ x,
    const unsigned short* __restrict__ w1p,
    const unsigned short* __restrict__ w2p,
    const float* __restrict__ cst,
    float* __restrict__ out)
{
    __shared__ alignas(16) unsigned short q[64 * 256];  // 32 KB, swizzled
    __shared__ alignas(16) float xs[4 * 1024];          // 16 KB, wave-private ping-pong

    const int b  = blockIdx.x;          // 2048 blocks
    const int n  = b >> 8;
    const int s0 = (b & 255) << 6;
    const float* xb = x   + (size_t)n * (256 * SPOS) + s0;
    float*       ob = out + (size_t)n * (256 * SPOS) + s0;

    const int t    = threadIdx.x;
    const int lane = t & 63;
    const int w    = t >> 6;            // wave id 0..3
    const int quad = lane >> 4;
    const int l15  = lane & 15;

    // ---- Phase 1 (R1 form, best measured): wave w owns channels 64w..64w+63.
    // All 16 float4 loads issued up front, then 8 quantize rounds through a
    // ping-pong xs strip (same-wave LDS ops are in-order; cross-lane reads OK).
    {
        const int g  = lane & 15;       // float4 group along p
        const int co = lane >> 4;       // 0..3
        float* xsw = xs + w * 1024;
        const float* src0 = xb + (size_t)(64 * w + co) * SPOS + 4 * g;
        floatx4 v[16];
        #pragma unroll
        for (int r = 0; r < 8; ++r) {
            v[2 * r]     = *(const floatx4*)(src0 + (size_t)(8 * r) * SPOS);
            v[2 * r + 1] = *(const floatx4*)(src0 + (size_t)(8 * r + 4) * SPOS);
        }
        #pragma unroll
        for (int r = 0; r < 8; ++r) {
            float* xr = xsw + (r & 1) * 512;
            // element p of channel-row cl lives at dword cl*64 + (p ^ 4*cl)
            *(floatx4*)&xr[co * 64 + ((4 * g) ^ (4 * co))]             = v[2 * r];
            *(floatx4*)&xr[(co + 4) * 64 + ((4 * g) ^ (4 * (co + 4)))] = v[2 * r + 1];
            short8 pk;
            #pragma unroll
            for (int c8 = 0; c8 < 8; ++c8)
                pk[c8] = (short)f2bf(posit_q(xr[c8 * 64 + (lane ^ (4 * c8))]));
            *(short8*)&q[qidx(lane, 8 * w + r)] = pk;   // cb = (64w+8r)/8
        }
    }
    __syncthreads();    // q fully populated

    floatx4 acc[4][4];
    #pragma unroll
    for (int i = 0; i < 4; ++i)
        #pragma unroll
        for (int jj = 0; jj < 4; ++jj)
            acc[i][jj] = (floatx4)0.0f;

    // ---- GEMM1: A = W1p (packed, coalesced, L2-hot), B = q ----
    #pragma unroll
    for (int kk = 0; kk < 256; kk += 32) {
        short8 af[4], bf[4];
        #pragma unroll
        for (int i = 0; i < 4; ++i)
            af[i] = *(const short8*)&w1p[(((w * 4 + i) * 8 + (kk >> 5)) * 64 + lane) * 8];
        #pragma unroll
        for (int jj = 0; jj < 4; ++jj)
            bf[jj] = *(const short8*)&q[qidx(16 * jj + l15, (kk >> 3) + quad)];
        #pragma unroll
        for (int i = 0; i < 4; ++i)
            #pragma unroll
            for (int jj = 0; jj < 4; ++jj)
                acc[i][jj] = __builtin_amdgcn_mfma_f32_16x16x32_bf16(af[i], bf[jj], acc[i][jj], 0, 0, 0);
    }

    // Prefetch GEMM2's first af set; L2 latency hides under epilogue-1 VALU.
    short8 af20[4];
    #pragma unroll
    for (int i = 0; i < 4; ++i)
        af20[i] = *(const short8*)&w2p[(((w * 4 + i) * 8 + 0) * 64 + lane) * 8];

    __syncthreads();   // all waves done reading q before overwrite

    const int mbase = w * 64;

    // ---- Epilogue 1: BN1 + ReLU + posit_q -> bf16 back into q[p][m] ----
    {
        const float* sc1 = cst;
        const float* bi1 = cst + 256;
        #pragma unroll
        for (int i = 0; i < 4; ++i) {
            const int m0 = mbase + 16 * i + quad * 4;
            float sc[4], bi[4];
            #pragma unroll
            for (int r = 0; r < 4; ++r) { sc[r] = sc1[m0 + r]; bi[r] = bi1[m0 + r]; }
            #pragma unroll
            for (int jj = 0; jj < 4; ++jj) {
                const int p = 16 * jj + l15;
                s4v h;
                #pragma unroll
                for (int r = 0; r < 4; ++r) {
                    float z = fmaf(acc[i][jj][r], sc[r], bi[r]);
                    z = fmaxf(z, 0.0f);
                    h[r] = (short)f2bf(posit_q_pos(z));
                }
                *(s4v*)&q[qidx(p, m0 >> 3) + (m0 & 7)] = h;
            }
        }
    }
    __syncthreads();

    // ---- GEMM2 (operand-SWAPPED, verified R6): D transposed so lane holds
    // acc[i][jj][r] = out[ch = 64w+16i+l15][pos = 16jj + 4*quad + r].
    #pragma unroll
    for (int i = 0; i < 4; ++i)
        #pragma unroll
        for (int jj = 0; jj < 4; ++jj)
            acc[i][jj] = (floatx4)0.0f;

    #pragma unroll
    for (int kk = 0; kk < 256; kk += 32) {
        short8 af[4], bf[4];
        #pragma unroll
        for (int i = 0; i < 4; ++i)
            af[i] = (kk == 0) ? af20[i]
                  : *(const short8*)&w2p[(((w * 4 + i) * 8 + (kk >> 5)) * 64 + lane) * 8];
        #pragma unroll
        for (int jj = 0; jj < 4; ++jj)
            bf[jj] = *(const short8*)&q[qidx(16 * jj + l15, (kk >> 3) + quad)];
        #pragma unroll
        for (int i = 0; i < 4; ++i)
            #pragma unroll
            for (int jj = 0; jj < 4; ++jj)
                acc[i][jj] = __builtin_amdgcn_mfma_f32_16x16x32_bf16(bf[jj], af[i], acc[i][jj], 0, 0, 0);
    }

    __syncthreads();   // all waves done reading q: safe to reuse as f32 staging

    // ---- Epilogue 2: LDS-transposed staging -> FULL-LINE stores.
    // R6/R7 lesson: 64B-per-row store chunks amplified WRITE_SIZE to ~250MB
    // (partial 128B-line writebacks). Here acc is staged into the free q
    // buffer (wave-private 8KB, 16B-granule XOR swizzle = q's measured-clean
    // bank pattern), read back transposed, so each residual load and each
    // out store covers 4 rows x 256B contiguous -- every 128B line touched
    // exactly once by exactly one instruction.
    {
        const float* sc2 = cst + 512;
        const float* bi2 = cst + 768;
        float* stg = (float*)q + w * 2048;   // 8 KB per wave
        #pragma unroll
        for (int h = 0; h < 2; ++h) {
            // stage half h (i = 2h, 2h+1): row chl = 16*i2 + l15, pos 16jj+4quad
            #pragma unroll
            for (int i2 = 0; i2 < 2; ++i2) {
                const int chl = 16 * i2 + l15;
                #pragma unroll
                for (int jj = 0; jj < 4; ++jj)
                    *(floatx4*)&stg[chl * 64 + 4 * ((4 * jj + quad) ^ l15)] = acc[2 * h + i2][jj];
            }
            // same-wave LDS ops are in-order: reads below see the writes above.
            #pragma unroll
            for (int k = 0; k < 8; ++k) {
                const int chl = 4 * k + quad;               // 4 rows/instr
                const int ch  = mbase + 32 * h + chl;
                const size_t off = (size_t)ch * SPOS + 4 * l15;  // 256B/row
                floatx4 v   = *(const floatx4*)&stg[chl * 64 + 4 * (l15 ^ (chl & 15))];
                floatx4 res = *(const floatx4*)(xb + off);
                const float sc = sc2[ch];
                const float bi = bi2[ch];
                floatx4 o;
                #pragma unroll
                for (int r = 0; r < 4; ++r)
                    o[r] = fmaxf(fmaf(v[r], sc, bi) + res[r], 0.0f);
                *(floatx4*)(ob + off) = o;
            }
            // half h+1's staging writes follow this half's reads in wave
            // program order -> no WAR hazard (wave-private region).
        }
    }
}

extern "C" void kernel_launch(void* const* d_in, const int* in_sizes, int n_in,
                              void* d_out, int out_size, void* d_ws, size_t ws_size,
                              hipStream_t stream) {
    const float* x   = (const float*)d_in[0];
    const float* w1  = (const float*)d_in[1];
    const float* b1  = (const float*)d_in[2];
    const float* g1  = (const float*)d_in[3];
    const float* be1 = (const float*)d_in[4];
    const float* m1  = (const float*)d_in[5];
    const float* v1  = (const float*)d_in[6];
    const float* w2  = (const float*)d_in[7];
    const float* b2  = (const float*)d_in[8];
    const float* g2  = (const float*)d_in[9];
    const float* be2 = (const float*)d_in[10];
    const float* m2  = (const float*)d_in[11];
    const float* v2  = (const float*)d_in[12];

    unsigned short* w1p = (unsigned short*)d_ws;
    unsigned short* w2p = w1p + 65536;
    float* cst = (float*)(w2p + 65536);   // scale1|bias1|scale2|bias2

    prep_kernel<<<256, 256, 0, stream>>>(w1, w2, b1, g1, be1, m1, v1,
                                         b2, g2, be2, m2, v2, w1p, w2p, cst);
    fused_kernel<<<2048, 256, 0, stream>>>(x, w1p, w2p, cst, (float*)d_out);
}

// Round 9
// 325.552 us; speedup vs baseline: 1.1100x; 1.0061x over previous
//
#include <hip/hip_runtime.h>

typedef __attribute__((ext_vector_type(8))) short short8;
typedef __attribute__((ext_vector_type(4))) short s4v;
typedef __attribute__((ext_vector_type(4))) float floatx4;

#define SPOS 16384

// round-to-nearest-even fp32 -> bf16 bits
__device__ __forceinline__ unsigned short f2bf(float f) {
    unsigned u = __float_as_uint(f);
    u += 0x7fffu + ((u >> 16) & 1u);
    return (unsigned short)(u >> 16);
}

// Branchless bit-twiddle posit quantizer (verified equivalent of the 128
// sequential where-passes).
__device__ __forceinline__ float posit_q(float x) {
    unsigned xu  = __float_as_uint(x);
    unsigned sgn = xu & 0x80000000u;
    unsigned au  = xu & 0x7fffffffu;
    unsigned m   = au & 0x007fffffu;
    unsigned r   = (au + 0x00080000u) & 0xfff00000u;
    bool bdry = (m & 0x000fffffu) == 0x00080000u;
    unsigned res;
    if (au >= 0x3f800000u) {                      // |x| >= 1
        res = r;
        if (m > 0x00700000u && m < 0x00780000u && au < 0x47700000u)
            res = (au & 0xff800000u) + 0x00800000u;   // -> 2^(E+1)
        if ((bdry && m != 0x00780000u) || au >= 0x47780000u)
            res = au;                              // boundaries & clamp unchanged
    } else {                                       // |x| < 1
        res = (m <= 0x00080000u || m >= 0x00780000u || bdry) ? au : r;
        if (au < 0x37880000u) res = au ? 0x37800000u : 0u;  // -> 2^-16 (0 stays 0)
    }
    return __uint_as_float(sgn | res);
}

// Same, for z >= 0 (post-ReLU) — sign handling dropped, bit-identical result.
__device__ __forceinline__ float posit_q_pos(float z) {
    unsigned au  = __float_as_uint(z);
    unsigned m   = au & 0x007fffffu;
    unsigned r   = (au + 0x00080000u) & 0xfff00000u;
    bool bdry = (m & 0x000fffffu) == 0x00080000u;
    unsigned res;
    if (au >= 0x3f800000u) {
        res = r;
        if (m > 0x00700000u && m < 0x00780000u && au < 0x47700000u)
            res = (au & 0xff800000u) + 0x00800000u;
        if ((bdry && m != 0x00780000u) || au >= 0x47780000u)
            res = au;
    } else {
        res = (m <= 0x00080000u || m >= 0x00780000u || bdry) ? au : r;
        if (au < 0x37880000u) res = au ? 0x37800000u : 0u;
    }
    return __uint_as_float(res);
}

// Quantize weights to bf16 in MFMA-FRAGMENT-PACKED order + fold BN constants.
// Packed layout: i = G*4096 + kb*512 + lane*8 + j  (G=row-group of 16, kb=K-block
// of 32, lane=wave lane, j=0..7) holds W[16G + (lane&15)][32kb + 8*(lane>>4) + j].
__global__ __launch_bounds__(256) void prep_kernel(
    const float* __restrict__ w1, const float* __restrict__ w2,
    const float* __restrict__ b1, const float* __restrict__ g1,
    const float* __restrict__ be1, const float* __restrict__ m1,
    const float* __restrict__ v1,
    const float* __restrict__ b2, const float* __restrict__ g2,
    const float* __restrict__ be2, const float* __restrict__ m2,
    const float* __restrict__ v2,
    unsigned short* __restrict__ w1p, unsigned short* __restrict__ w2p,
    float* __restrict__ cst)
{
    int i = blockIdx.x * 256 + threadIdx.x;
    if (i < 65536) {
        const int j    = i & 7;
        const int lane = (i >> 3) & 63;
        const int kb   = (i >> 9) & 7;
        const int G    = i >> 12;
        const int row  = 16 * G + (lane & 15);
        const int k    = 32 * kb + 8 * (lane >> 4) + j;
        w1p[i] = f2bf(posit_q(w1[row * 256 + k]));
        w2p[i] = f2bf(posit_q(w2[row * 256 + k]));
        if (i < 256) {
            float inv1 = g1[i] / sqrtf(v1[i] + 1e-5f);
            cst[i]       = inv1;
            cst[256 + i] = fmaf(b1[i], inv1, be1[i] - m1[i] * inv1);
            float inv2 = g2[i] / sqrtf(v2[i] + 1e-5f);
            cst[512 + i] = inv2;
            cst[768 + i] = fmaf(b2[i], inv2, be2[i] - m2[i] * inv2);
        }
    }
}

// q layout: 32 rows (p) x 32 column-blocks of 8 bf16, XOR-swizzled:
// block cb stored at physical block (cb ^ p) -> bank-minimal (R1-verified).
__device__ __forceinline__ int qidx(int p, int cb) {
    return p * 256 + ((cb ^ (p & 31)) << 3);
}

// 32-POSITION TILE (R9): halves acc (32 VGPR) and LDS (24 KB) so 4+ blocks/CU
// fit WITHOUT the R2 spill disaster. 4096 blocks; occupancy was the binding
// constraint at N=64 (29% measured, all pipes <35% = latency-bound).
__global__ __launch_bounds__(256, 4) void fused_kernel(
    const float* __restrict__ x,
    const unsigned short* __restrict__ w1p,
    const unsigned short* __restrict__ w2p,
    const float* __restrict__ cst,
    float* __restrict__ out)
{
    __shared__ alignas(16) unsigned short q[32 * 256];  // 16 KB, swizzled
    __shared__ alignas(16) float xs[4 * 512];           // 8 KB (2 KB/wave strip)

    const int b  = blockIdx.x;          // 4096 blocks
    const int n  = b >> 9;              // 512 tiles per batch image
    const int s0 = (b & 511) << 5;      // 32-position tile
    const float* xb = x   + (size_t)n * (256 * SPOS) + s0;
    float*       ob = out + (size_t)n * (256 * SPOS) + s0;

    const int t    = threadIdx.x;
    const int lane = t & 63;
    const int w    = t >> 6;            // wave id 0..3
    const int quad = lane >> 4;
    const int l15  = lane & 15;

    // ---- Phase 1: wave w owns channels 64w..64w+63, 32 positions.
    // 8 float4 loads up front (8 ch-rows x 128 B each, fully coalesced),
    // then 4 double-rounds: 16 ch -> xs strip (granule-XOR, conflict-free)
    // -> all 64 lanes quantize+pack (p5 = lane&31, half = lane>>5).
    {
        const int g  = lane & 7;        // pos granule (4 pos)
        const int co = lane >> 3;       // 0..7 channel within block
        float* xsw = xs + w * 512;
        const float* src0 = xb + (size_t)(64 * w + co) * SPOS + 4 * g;
        floatx4 v[8];
        #pragma unroll
        for (int r = 0; r < 8; ++r)
            v[r] = *(const floatx4*)(src0 + (size_t)(8 * r) * SPOS);
        const int p5 = lane & 31, half = lane >> 5;
        #pragma unroll
        for (int dr = 0; dr < 4; ++dr) {
            // rows cl=co and cl=co+8; (co+8)&7 == co so same XOR key
            *(floatx4*)&xsw[co * 32 + 4 * (g ^ co)]       = v[2 * dr];
            *(floatx4*)&xsw[(co + 8) * 32 + 4 * (g ^ co)] = v[2 * dr + 1];
            short8 pk;
            #pragma unroll
            for (int j = 0; j < 8; ++j) {
                const int cl = 8 * half + j;
                const float val = xsw[cl * 32 + 4 * ((p5 >> 2) ^ (cl & 7)) + (p5 & 3)];
                pk[j] = (short)f2bf(posit_q(val));
            }
            *(short8*)&q[qidx(p5, 8 * w + 2 * dr + half)] = pk;
            // next dr overwrites strip: same-wave LDS ops are in-order, safe
        }
    }
    __syncthreads();    // q fully populated

    floatx4 acc[4][2];
    #pragma unroll
    for (int i = 0; i < 4; ++i)
        #pragma unroll
        for (int jj = 0; jj < 2; ++jj)
            acc[i][jj] = (floatx4)0.0f;

    // ---- GEMM1: A = W1p (packed, L2-hot), B = q ----
    #pragma unroll
    for (int kk = 0; kk < 8; ++kk) {
        short8 af[4], bf[2];
        #pragma unroll
        for (int i = 0; i < 4; ++i)
            af[i] = *(const short8*)&w1p[(((w * 4 + i) * 8 + kk) * 64 + lane) * 8];
        #pragma unroll
        for (int jj = 0; jj < 2; ++jj)
            bf[jj] = *(const short8*)&q[qidx(16 * jj + l15, 4 * kk + quad)];
        #pragma unroll
        for (int i = 0; i < 4; ++i)
            #pragma unroll
            for (int jj = 0; jj < 2; ++jj)
                acc[i][jj] = __builtin_amdgcn_mfma_f32_16x16x32_bf16(af[i], bf[jj], acc[i][jj], 0, 0, 0);
    }

    // Prefetch GEMM2's first af set; L2 latency hides under epilogue-1 VALU.
    short8 af20[4];
    #pragma unroll
    for (int i = 0; i < 4; ++i)
        af20[i] = *(const short8*)&w2p[(((w * 4 + i) * 8 + 0) * 64 + lane) * 8];

    __syncthreads();   // all waves done reading q before overwrite

    const int mbase = w * 64;

    // ---- Epilogue 1: BN1 + ReLU + posit_q -> bf16 back into q[p][m] ----
    {
        const float* sc1 = cst;
        const float* bi1 = cst + 256;
        #pragma unroll
        for (int i = 0; i < 4; ++i) {
            const int m0 = mbase + 16 * i + quad * 4;
            float sc[4], bi[4];
            #pragma unroll
            for (int r = 0; r < 4; ++r) { sc[r] = sc1[m0 + r]; bi[r] = bi1[m0 + r]; }
            #pragma unroll
            for (int jj = 0; jj < 2; ++jj) {
                const int p = 16 * jj + l15;
                s4v h;
                #pragma unroll
                for (int r = 0; r < 4; ++r) {
                    float z = fmaf(acc[i][jj][r], sc[r], bi[r]);
                    z = fmaxf(z, 0.0f);
                    h[r] = (short)f2bf(posit_q_pos(z));
                }
                *(s4v*)&q[qidx(p, m0 >> 3) + (m0 & 7)] = h;
            }
        }
    }
    __syncthreads();

    // ---- GEMM2 (operand-SWAPPED, R6-verified): lane holds
    // acc[i][jj][r] = out[ch = 64w+16i+l15][pos = 16jj + 4*quad + r].
    #pragma unroll
    for (int i = 0; i < 4; ++i)
        #pragma unroll
        for (int jj = 0; jj < 2; ++jj)
            acc[i][jj] = (floatx4)0.0f;

    #pragma unroll
    for (int kk = 0; kk < 8; ++kk) {
        short8 af[4], bf[2];
        #pragma unroll
        for (int i = 0; i < 4; ++i)
            af[i] = (kk == 0) ? af20[i]
                  : *(const short8*)&w2p[(((w * 4 + i) * 8 + kk) * 64 + lane) * 8];
        #pragma unroll
        for (int jj = 0; jj < 2; ++jj)
            bf[jj] = *(const short8*)&q[qidx(16 * jj + l15, 4 * kk + quad)];
        #pragma unroll
        for (int i = 0; i < 4; ++i)
            #pragma unroll
            for (int jj = 0; jj < 2; ++jj)
                acc[i][jj] = __builtin_amdgcn_mfma_f32_16x16x32_bf16(bf[jj], af[i], acc[i][jj], 0, 0, 0);
    }

    __syncthreads();   // all waves done reading q: reuse as f32 staging

    // ---- Epilogue 2 (R8-proven full-line scheme, adapted to N=32):
    // stage acc into free q (4 KB/wave, granule-XOR), read back transposed;
    // each residual load / out store = 8 ch-rows x 128 B = full lines,
    // each line touched exactly once by one instruction.
    {
        const float* sc2 = cst + 512;
        const float* bi2 = cst + 768;
        float* stg = (float*)q + w * 1024;   // 4 KB per wave
        const int row_g = lane >> 3, g = lane & 7;

        // pre-issue ALL residual loads: HBM/L3 latency hides under staging
        floatx4 res[2][4];
        #pragma unroll
        for (int h = 0; h < 2; ++h)
            #pragma unroll
            for (int k = 0; k < 4; ++k) {
                const int ch = mbase + 32 * h + 8 * k + row_g;
                res[h][k] = *(const floatx4*)(xb + (size_t)ch * SPOS + 4 * g);
            }

        #pragma unroll
        for (int h = 0; h < 2; ++h) {
            #pragma unroll
            for (int i2 = 0; i2 < 2; ++i2) {
                const int chl = 16 * i2 + l15;
                #pragma unroll
                for (int jj = 0; jj < 2; ++jj)
                    *(floatx4*)&stg[chl * 32 + 4 * ((4 * jj + quad) ^ (chl & 7))] = acc[2 * h + i2][jj];
            }
            // same-wave LDS in-order: reads below see writes above
            #pragma unroll
            for (int k = 0; k < 4; ++k) {
                const int chl = 8 * k + row_g;            // chl&7 == row_g
                const int ch  = mbase + 32 * h + chl;
                floatx4 v = *(const floatx4*)&stg[chl * 32 + 4 * (g ^ row_g)];
                const float sc = sc2[ch];
                const float bi = bi2[ch];
                floatx4 o;
                #pragma unroll
                for (int r = 0; r < 4; ++r)
                    o[r] = fmaxf(fmaf(v[r], sc, bi) + res[h][k][r], 0.0f);
                *(floatx4*)(ob + (size_t)ch * SPOS + 4 * g) = o;
            }
            // h=1 staging writes follow h=0 reads in program order: no WAR
        }
    }
}

extern "C" void kernel_launch(void* const* d_in, const int* in_sizes, int n_in,
                              void* d_out, int out_size, void* d_ws, size_t ws_size,
                              hipStream_t stream) {
    const float* x   = (const float*)d_in[0];
    const float* w1  = (const float*)d_in[1];
    const float* b1  = (const float*)d_in[2];
    const float* g1  = (const float*)d_in[3];
    const float* be1 = (const float*)d_in[4];
    const float* m1  = (const float*)d_in[5];
    const float* v1  = (const float*)d_in[6];
    const float* w2  = (const float*)d_in[7];
    const float* b2  = (const float*)d_in[8];
    const float* g2  = (const float*)d_in[9];
    const float* be2 = (const float*)d_in[10];
    const float* m2  = (const float*)d_in[11];
    const float* v2  = (const float*)d_in[12];

    unsigned short* w1p = (unsigned short*)d_ws;
    unsigned short* w2p = w1p + 65536;
    float* cst = (float*)(w2p + 65536);   // scale1|bias1|scale2|bias2

    prep_kernel<<<256, 256, 0, stream>>>(w1, w2, b1, g1, be1, m1, v1,
                                         b2, g2, be2, m2, v2, w1p, w2p, cst);
    fused_kernel<<<4096, 256, 0, stream>>>(x, w1p, w2p, cst, (float*)d_out);
}

// Round 10
// 322.733 us; speedup vs baseline: 1.1197x; 1.0087x over previous
//
#include <hip/hip_runtime.h>

typedef __attribute__((ext_vector_type(8))) short short8;
typedef __attribute__((ext_vector_type(4))) short s4v;
typedef __attribute__((ext_vector_type(4))) float floatx4;

#define SPOS 16384

// round-to-nearest-even fp32 -> bf16 bits
__device__ __forceinline__ unsigned short f2bf(float f) {
    unsigned u = __float_as_uint(f);
    u += 0x7fffu + ((u >> 16) & 1u);
    return (unsigned short)(u >> 16);
}

// Branchless bit-twiddle posit quantizer (verified equivalent of the 128
// sequential where-passes).
__device__ __forceinline__ float posit_q(float x) {
    unsigned xu  = __float_as_uint(x);
    unsigned sgn = xu & 0x80000000u;
    unsigned au  = xu & 0x7fffffffu;
    unsigned m   = au & 0x007fffffu;
    unsigned r   = (au + 0x00080000u) & 0xfff00000u;
    bool bdry = (m & 0x000fffffu) == 0x00080000u;
    unsigned res;
    if (au >= 0x3f800000u) {                      // |x| >= 1
        res = r;
        if (m > 0x00700000u && m < 0x00780000u && au < 0x47700000u)
            res = (au & 0xff800000u) + 0x00800000u;   // -> 2^(E+1)
        if ((bdry && m != 0x00780000u) || au >= 0x47780000u)
            res = au;                              // boundaries & clamp unchanged
    } else {                                       // |x| < 1
        res = (m <= 0x00080000u || m >= 0x00780000u || bdry) ? au : r;
        if (au < 0x37880000u) res = au ? 0x37800000u : 0u;  // -> 2^-16 (0 stays 0)
    }
    return __uint_as_float(sgn | res);
}

// Same, for z >= 0 (post-ReLU) — sign handling dropped, bit-identical result.
__device__ __forceinline__ float posit_q_pos(float z) {
    unsigned au  = __float_as_uint(z);
    unsigned m   = au & 0x007fffffu;
    unsigned r   = (au + 0x00080000u) & 0xfff00000u;
    bool bdry = (m & 0x000fffffu) == 0x00080000u;
    unsigned res;
    if (au >= 0x3f800000u) {
        res = r;
        if (m > 0x00700000u && m < 0x00780000u && au < 0x47700000u)
            res = (au & 0xff800000u) + 0x00800000u;
        if ((bdry && m != 0x00780000u) || au >= 0x47780000u)
            res = au;
    } else {
        res = (m <= 0x00080000u || m >= 0x00780000u || bdry) ? au : r;
        if (au < 0x37880000u) res = au ? 0x37800000u : 0u;
    }
    return __uint_as_float(res);
}

// Quantize weights to bf16 in MFMA-FRAGMENT-PACKED order + fold BN constants.
// Packed layout: i = G*4096 + kb*512 + lane*8 + j  (G=row-group of 16, kb=K-block
// of 32, lane=wave lane, j=0..7) holds W[16G + (lane&15)][32kb + 8*(lane>>4) + j].
__global__ __launch_bounds__(256) void prep_kernel(
    const float* __restrict__ w1, const float* __restrict__ w2,
    const float* __restrict__ b1, const float* __restrict__ g1,
    const float* __restrict__ be1, const float* __restrict__ m1,
    const float* __restrict__ v1,
    const float* __restrict__ b2, const float* __restrict__ g2,
    const float* __restrict__ be2, const float* __restrict__ m2,
    const float* __restrict__ v2,
    unsigned short* __restrict__ w1p, unsigned short* __restrict__ w2p,
    float* __restrict__ cst)
{
    int i = blockIdx.x * 256 + threadIdx.x;
    if (i < 65536) {
        const int j    = i & 7;
        const int lane = (i >> 3) & 63;
        const int kb   = (i >> 9) & 7;
        const int G    = i >> 12;
        const int row  = 16 * G + (lane & 15);
        const int k    = 32 * kb + 8 * (lane >> 4) + j;
        w1p[i] = f2bf(posit_q(w1[row * 256 + k]));
        w2p[i] = f2bf(posit_q(w2[row * 256 + k]));
        if (i < 256) {
            float inv1 = g1[i] / sqrtf(v1[i] + 1e-5f);
            cst[i]       = inv1;
            cst[256 + i] = fmaf(b1[i], inv1, be1[i] - m1[i] * inv1);
            float inv2 = g2[i] / sqrtf(v2[i] + 1e-5f);
            cst[512 + i] = inv2;
            cst[768 + i] = fmaf(b2[i], inv2, be2[i] - m2[i] * inv2);
        }
    }
}

// q layout: 32 rows (p) x 32 column-blocks of 8 bf16, XOR-swizzled:
// block cb stored at physical block (cb ^ p) -> bank-minimal (R1-verified).
__device__ __forceinline__ int qidx(int p, int cb) {
    return p * 256 + ((cb ^ (p & 31)) << 3);
}

// R10: DOUBLE-BUFFERED q (q1 = quantized x, q2 = quantized z1) cuts barriers
// 4 -> 2: epilogue-1 can write q2 while other waves still read q1 in GEMM1,
// and epilogue-2 can stage into q1 while other waves still read q2 in GEMM2.
// Phase-1 transpose scratch lives in each wave's private quarter of q2
// (dead at that point), so LDS stays 32 KB -> up to 5 blocks/CU.
__global__ __launch_bounds__(256, 4) void fused_kernel(
    const float* __restrict__ x,
    const unsigned short* __restrict__ w1p,
    const unsigned short* __restrict__ w2p,
    const float* __restrict__ cst,
    float* __restrict__ out)
{
    __shared__ alignas(16) unsigned short q1[32 * 256];  // 16 KB
    __shared__ alignas(16) unsigned short q2[32 * 256];  // 16 KB

    const int b  = blockIdx.x;          // 4096 blocks
    const int n  = b >> 9;              // 512 tiles per batch image
    const int s0 = (b & 511) << 5;      // 32-position tile
    const float* xb = x   + (size_t)n * (256 * SPOS) + s0;
    float*       ob = out + (size_t)n * (256 * SPOS) + s0;

    const int t    = threadIdx.x;
    const int lane = t & 63;
    const int w    = t >> 6;            // wave id 0..3
    const int quad = lane >> 4;
    const int l15  = lane & 15;

    // ---- Phase 1: wave w owns channels 64w..64w+63, 32 positions.
    // 8 float4 loads up front, then 4 double-rounds through a scratch strip
    // in this wave's private quarter of q2 (granule-XOR, conflict-free).
    {
        const int g  = lane & 7;        // pos granule (4 pos)
        const int co = lane >> 3;       // 0..7 channel within block
        float* xsw = (float*)q2 + w * 1024;   // 4 KB/wave; strip uses 2 KB
        const float* src0 = xb + (size_t)(64 * w + co) * SPOS + 4 * g;
        floatx4 v[8];
        #pragma unroll
        for (int r = 0; r < 8; ++r)
            v[r] = *(const floatx4*)(src0 + (size_t)(8 * r) * SPOS);
        const int p5 = lane & 31, half = lane >> 5;
        #pragma unroll
        for (int dr = 0; dr < 4; ++dr) {
            // rows cl=co and cl=co+8; (co+8)&7 == co so same XOR key
            *(floatx4*)&xsw[co * 32 + 4 * (g ^ co)]       = v[2 * dr];
            *(floatx4*)&xsw[(co + 8) * 32 + 4 * (g ^ co)] = v[2 * dr + 1];
            short8 pk;
            #pragma unroll
            for (int j = 0; j < 8; ++j) {
                const int cl = 8 * half + j;
                const float val = xsw[cl * 32 + 4 * ((p5 >> 2) ^ (cl & 7)) + (p5 & 3)];
                pk[j] = (short)f2bf(posit_q(val));
            }
            *(short8*)&q1[qidx(p5, 8 * w + 2 * dr + half)] = pk;
            // next dr overwrites strip: same-wave LDS ops are in-order, safe
        }
    }
    __syncthreads();    // BARRIER 1: q1 populated; q2 scratch use finished

    floatx4 acc[4][2];
    #pragma unroll
    for (int i = 0; i < 4; ++i)
        #pragma unroll
        for (int jj = 0; jj < 2; ++jj)
            acc[i][jj] = (floatx4)0.0f;

    // ---- GEMM1: A = W1p (packed, L2-hot), B = q1 ----
    #pragma unroll
    for (int kk = 0; kk < 8; ++kk) {
        short8 af[4], bf[2];
        #pragma unroll
        for (int i = 0; i < 4; ++i)
            af[i] = *(const short8*)&w1p[(((w * 4 + i) * 8 + kk) * 64 + lane) * 8];
        #pragma unroll
        for (int jj = 0; jj < 2; ++jj)
            bf[jj] = *(const short8*)&q1[qidx(16 * jj + l15, 4 * kk + quad)];
        #pragma unroll
        for (int i = 0; i < 4; ++i)
            #pragma unroll
            for (int jj = 0; jj < 2; ++jj)
                acc[i][jj] = __builtin_amdgcn_mfma_f32_16x16x32_bf16(af[i], bf[jj], acc[i][jj], 0, 0, 0);
    }

    // Prefetch GEMM2's first af set; L2 latency hides under epilogue-1 VALU.
    short8 af20[4];
    #pragma unroll
    for (int i = 0; i < 4; ++i)
        af20[i] = *(const short8*)&w2p[(((w * 4 + i) * 8 + 0) * 64 + lane) * 8];

    const int mbase = w * 64;

    // ---- Epilogue 1 (NO barrier before): BN1 + ReLU + posit_q -> q2.
    // This wave's GEMM1 reads of q1 are done (program order); its q2 writes
    // hit wave-exclusive cb blocks (m in this wave's 64-channel range), and
    // all q2 scratch use ended before barrier 1 -> no hazard with waves
    // still running GEMM1.
    {
        const float* sc1 = cst;
        const float* bi1 = cst + 256;
        #pragma unroll
        for (int i = 0; i < 4; ++i) {
            const int m0 = mbase + 16 * i + quad * 4;
            float sc[4], bi[4];
            #pragma unroll
            for (int r = 0; r < 4; ++r) { sc[r] = sc1[m0 + r]; bi[r] = bi1[m0 + r]; }
            #pragma unroll
            for (int jj = 0; jj < 2; ++jj) {
                const int p = 16 * jj + l15;
                s4v h;
                #pragma unroll
                for (int r = 0; r < 4; ++r) {
                    float z = fmaf(acc[i][jj][r], sc[r], bi[r]);
                    z = fmaxf(z, 0.0f);
                    h[r] = (short)f2bf(posit_q_pos(z));
                }
                *(s4v*)&q2[qidx(p, m0 >> 3) + (m0 & 7)] = h;
            }
        }
    }
    __syncthreads();    // BARRIER 2: q2 (z1) ready; also: every wave has
                        // finished GEMM1 -> q1 is reusable below.

    // ---- GEMM2 (operand-SWAPPED, R6-verified): lane holds
    // acc[i][jj][r] = out[ch = 64w+16i+l15][pos = 16jj + 4*quad + r].
    #pragma unroll
    for (int i = 0; i < 4; ++i)
        #pragma unroll
        for (int jj = 0; jj < 2; ++jj)
            acc[i][jj] = (floatx4)0.0f;

    #pragma unroll
    for (int kk = 0; kk < 8; ++kk) {
        short8 af[4], bf[2];
        #pragma unroll
        for (int i = 0; i < 4; ++i)
            af[i] = (kk == 0) ? af20[i]
                  : *(const short8*)&w2p[(((w * 4 + i) * 8 + kk) * 64 + lane) * 8];
        #pragma unroll
        for (int jj = 0; jj < 2; ++jj)
            bf[jj] = *(const short8*)&q2[qidx(16 * jj + l15, 4 * kk + quad)];
        #pragma unroll
        for (int i = 0; i < 4; ++i)
            #pragma unroll
            for (int jj = 0; jj < 2; ++jj)
                acc[i][jj] = __builtin_amdgcn_mfma_f32_16x16x32_bf16(bf[jj], af[i], acc[i][jj], 0, 0, 0);
    }

    // ---- Epilogue 2 (NO barrier before; R8 full-line scheme): stage acc
    // into this wave's private quarter of q1 (free since barrier 2), read
    // back transposed; each residual load / out store = 8 ch-rows x 128 B
    // full lines, each line touched exactly once by one instruction.
    {
        const float* sc2 = cst + 512;
        const float* bi2 = cst + 768;
        float* stg = (float*)q1 + w * 1024;   // 4 KB per wave
        const int row_g = lane >> 3, g = lane & 7;

        // pre-issue ALL residual loads: HBM/L3 latency hides under staging
        floatx4 res[2][4];
        #pragma unroll
        for (int h = 0; h < 2; ++h)
            #pragma unroll
            for (int k = 0; k < 4; ++k) {
                const int ch = mbase + 32 * h + 8 * k + row_g;
                res[h][k] = *(const floatx4*)(xb + (size_t)ch * SPOS + 4 * g);
            }

        #pragma unroll
        for (int h = 0; h < 2; ++h) {
            #pragma unroll
            for (int i2 = 0; i2 < 2; ++i2) {
                const int chl = 16 * i2 + l15;
                #pragma unroll
                for (int jj = 0; jj < 2; ++jj)
                    *(floatx4*)&stg[chl * 32 + 4 * ((4 * jj + quad) ^ (chl & 7))] = acc[2 * h + i2][jj];
            }
            // same-wave LDS in-order: reads below see writes above
            #pragma unroll
            for (int k = 0; k < 4; ++k) {
                const int chl = 8 * k + row_g;            // chl&7 == row_g
                const int ch  = mbase + 32 * h + chl;
                floatx4 v = *(const floatx4*)&stg[chl * 32 + 4 * (g ^ row_g)];
                const float sc = sc2[ch];
                const float bi = bi2[ch];
                floatx4 o;
                #pragma unroll
                for (int r = 0; r < 4; ++r)
                    o[r] = fmaxf(fmaf(v[r], sc, bi) + res[h][k][r], 0.0f);
                *(floatx4*)(ob + (size_t)ch * SPOS + 4 * g) = o;
            }
            // h=1 staging writes follow h=0 reads in program order: no WAR
        }
    }
}

extern "C" void kernel_launch(void* const* d_in, const int* in_sizes, int n_in,
                              void* d_out, int out_size, void* d_ws, size_t ws_size,
                              hipStream_t stream) {
    const float* x   = (const float*)d_in[0];
    const float* w1  = (const float*)d_in[1];
    const float* b1  = (const float*)d_in[2];
    const float* g1  = (const float*)d_in[3];
    const float* be1 = (const float*)d_in[4];
    const float* m1  = (const float*)d_in[5];
    const float* v1  = (const float*)d_in[6];
    const float* w2  = (const float*)d_in[7];
    const float* b2  = (const float*)d_in[8];
    const float* g2  = (const float*)d_in[9];
    const float* be2 = (const float*)d_in[10];
    const float* m2  = (const float*)d_in[11];
    const float* v2  = (const float*)d_in[12];

    unsigned short* w1p = (unsigned short*)d_ws;
    unsigned short* w2p = w1p + 65536;
    float* cst = (float*)(w2p + 65536);   // scale1|bias1|scale2|bias2

    prep_kernel<<<256, 256, 0, stream>>>(w1, w2, b1, g1, be1, m1, v1,
                                         b2, g2, be2, m2, v2, w1p, w2p, cst);
    fused_kernel<<<4096, 256, 0, stream>>>(x, w1p, w2p, cst, (float*)d_out);
}